// Round 6
// baseline (135.677 us; speedup 1.0000x reference)
//
#include <hip/hip_runtime.h>

#define TT 32
#define EMB 256
#define HEAD 64
#define NI 8   // items per wave; grid = 8192/(4*NI) = 256 = one block per CU

typedef __attribute__((ext_vector_type(8)))  short    bf16x8;
typedef __attribute__((ext_vector_type(16))) float    f32x16;
typedef __attribute__((ext_vector_type(4)))  float    f32x4;
typedef __attribute__((ext_vector_type(4)))  unsigned uint4v;

__device__ __forceinline__ unsigned bfr(float f) {   // bf16 bits (RNE), low 16
  unsigned u = __builtin_bit_cast(unsigned, f);
  u += 0x7fffu + ((u >> 16) & 1u);
  return u >> 16;
}
__device__ __forceinline__ unsigned pk2(float a, float b) {  // lo=a, hi=b
  unsigned r;
  asm("v_cvt_pk_bf16_f32 %0, %1, %2" : "=v"(r) : "v"(a), "v"(b));
  return r;
}
__device__ __forceinline__ void plswap(unsigned a, unsigned b,
                                       unsigned& x, unsigned& y) {
  auto r = __builtin_amdgcn_permlane32_swap(a, b, false, false);
  x = r[0]; y = r[1];
}

// Wt[n][k] = W_{n/64}[k][n%64] bf16, stored SWIZZLED: u16 idx = n*256 + (k ^ ((n&7)<<3))
__global__ void prep_weights(const float* __restrict__ Wq,
                             const float* __restrict__ Wk,
                             const float* __restrict__ Wv,
                             unsigned short* __restrict__ Wt) {
  int idx = blockIdx.x * 256 + threadIdx.x;   // 192*256 total
  int n = idx >> 8, k = idx & 255;
  const float* W = (n < 64) ? Wq : (n < 128) ? Wk : Wv;
  Wt[n * 256 + (k ^ ((n & 7) << 3))] = (unsigned short)bfr(W[k * 64 + (n & 63)]);
}

// block = 4 waves; Wt staged once in LDS (96 KB); each wave computes NI items.
// X prefetched TWO items deep in VGPR ping-pong buffers F0/F1; counted
// vmcnt(63) wait keeps ~63 vector-mem ops in flight at all times (T4).
__global__ __launch_bounds__(256, 1)
void attn_kernel(const float* __restrict__ X,
                 const unsigned short* __restrict__ Wt,
                 const float* __restrict__ bq,
                 const float* __restrict__ bv,
                 float* __restrict__ out) {
  __shared__ unsigned short sW[192 * 256];   // 96 KB, swizzled layout

  const int tid  = threadIdx.x;
  const int wid  = tid >> 6;
  const int lane = tid & 63;
  const int lo   = lane & 31;   // MFMA tile row/col
  const int hi   = lane >> 5;   // k-half selector

  // ---- stage Wt -> LDS: linear 24 KB per wave (layout pre-swizzled) ----
  {
    const unsigned short* src = Wt + wid * 12288 + lane * 8;
#pragma unroll
    for (int i = 0; i < 24; ++i) {
      __builtin_amdgcn_global_load_lds(
          (const __attribute__((address_space(1))) void*)(src + i * 512),
          (__attribute__((address_space(3))) void*)(&sW[wid * 12288 + i * 512]),
          16, 0, 0);
    }
  }

  const long itemBase = (long)blockIdx.x * (4 * NI) + wid * NI;
  const float* Xb0 = X + itemBase * (TT * EMB);
  float* ob0 = out + itemBase * (TT * HEAD);

  // ---- loop-invariant bias regs ----
  f32x16 bQ2[2];
#pragma unroll
  for (int nt = 0; nt < 2; ++nt)
#pragma unroll
    for (int g = 0; g < 4; ++g) {
      f32x4 t = *(const f32x4*)(bq + nt * 32 + g * 8 + hi * 4);
#pragma unroll
      for (int q = 0; q < 4; ++q) bQ2[nt][g * 4 + q] = t[q];
    }
  // bv folds into PV accumulator init (softmax rows sum to 1); bk cancels.
  const float bv0 = bv[lo], bv1 = bv[32 + lo];

  const float* XpBase = Xb0 + lo * EMB + hi * 8;

#define ISSUE(Fb, jj)                                                        \
  do {                                                                       \
    const float* Xp_ = XpBase + (jj) * (TT * EMB);                           \
    _Pragma("unroll")                                                        \
    for (int i_ = 0; i_ < 32; ++i_)                                          \
      Fb[i_] = *(const f32x4*)(Xp_ + (i_ >> 1) * 16 + (i_ & 1) * 4);         \
  } while (0)

  // ---- prologue: items 0 and 1 in flight ----
  f32x4 F0[32], F1[32];
  ISSUE(F0, 0);
  ISSUE(F1, 1);

  __syncthreads();   // drains vmcnt+lgkmcnt: sW, F0, F1 all ready

  // One body: wait -> cvt -> issue(jj+2) -> compute/store item jj.
  // Queue invariant at wait: <=96 ops issued after item jj's 32 loads
  // (2x32 newer loads interleaved with 2x32 stores); vmcnt(63) => all of
  // item jj's loads retired (in-order), ~63 ops stay in flight.
#define BODY(Fb, jj)                                                         \
  do {                                                                       \
    asm volatile("s_waitcnt vmcnt(63)" ::: "memory");                        \
    __builtin_amdgcn_sched_barrier(0);                                       \
    uint4v Bf[16];                                                           \
    _Pragma("unroll")                                                        \
    for (int kk = 0; kk < 16; ++kk) {                                        \
      Bf[kk][0] = pk2(Fb[kk * 2][0],     Fb[kk * 2][1]);                     \
      Bf[kk][1] = pk2(Fb[kk * 2][2],     Fb[kk * 2][3]);                     \
      Bf[kk][2] = pk2(Fb[kk * 2 + 1][0], Fb[kk * 2 + 1][1]);                 \
      Bf[kk][3] = pk2(Fb[kk * 2 + 1][2], Fb[kk * 2 + 1][3]);                 \
    }                                                                        \
    __builtin_amdgcn_sched_barrier(0);                                       \
    if ((jj) + 2 < NI) { ISSUE(Fb, (jj) + 2); }                              \
    __builtin_amdgcn_sched_barrier(0);                                       \
    f32x16 aQ[2], aK[2], aV[2];                                              \
    aQ[0] = bQ2[0]; aQ[1] = bQ2[1];                                          \
    _Pragma("unroll")                                                        \
    for (int nt = 0; nt < 2; ++nt)                                           \
      _Pragma("unroll")                                                      \
      for (int r = 0; r < 16; ++r) { aK[nt][r] = 0.0f; aV[nt][r] = 0.0f; }   \
    _Pragma("unroll")                                                        \
    for (int kk = 0; kk < 16; ++kk) {                                        \
      bf16x8 a = __builtin_bit_cast(bf16x8, Bf[kk]);                         \
      const int csw = (kk * 16 + hi * 8) ^ ((lo & 7) << 3);                  \
      _Pragma("unroll")                                                      \
      for (int nt = 0; nt < 2; ++nt) {                                       \
        bf16x8 wq = *(const bf16x8*)&sW[(nt * 32 + lo) * 256 + csw];         \
        aQ[nt] = __builtin_amdgcn_mfma_f32_32x32x16_bf16(wq, a, aQ[nt], 0, 0, 0); \
        bf16x8 wk = *(const bf16x8*)&sW[(64 + nt * 32 + lo) * 256 + csw];    \
        aK[nt] = __builtin_amdgcn_mfma_f32_32x32x16_bf16(wk, a, aK[nt], 0, 0, 0); \
        bf16x8 wv = *(const bf16x8*)&sW[(128 + nt * 32 + lo) * 256 + csw];   \
        aV[nt] = __builtin_amdgcn_mfma_f32_32x32x16_bf16(a, wv, aV[nt], 0, 0, 0); \
      }                                                                      \
    }                                                                        \
    unsigned Qp[2][4][2], Kp[2][4][2], Vp[2][4][2];                          \
    _Pragma("unroll")                                                        \
    for (int nt = 0; nt < 2; ++nt)                                           \
      _Pragma("unroll")                                                      \
      for (int g = 0; g < 4; ++g) {                                          \
        Qp[nt][g][0] = pk2(aQ[nt][g * 4 + 0], aQ[nt][g * 4 + 1]);            \
        Qp[nt][g][1] = pk2(aQ[nt][g * 4 + 2], aQ[nt][g * 4 + 3]);            \
        Kp[nt][g][0] = pk2(aK[nt][g * 4 + 0], aK[nt][g * 4 + 1]);            \
        Kp[nt][g][1] = pk2(aK[nt][g * 4 + 2], aK[nt][g * 4 + 3]);            \
        Vp[nt][g][0] = pk2(aV[nt][g * 4 + 0], aV[nt][g * 4 + 1]);            \
        Vp[nt][g][1] = pk2(aV[nt][g * 4 + 2], aV[nt][g * 4 + 3]);            \
      }                                                                      \
    f32x16 wei;                                                              \
    _Pragma("unroll")                                                        \
    for (int r = 0; r < 16; ++r) wei[r] = 0.0f;                              \
    _Pragma("unroll")                                                        \
    for (int kk = 0; kk < 4; ++kk) {                                         \
      const int nt = kk >> 1, g0 = (2 * kk) & 3, g1 = (2 * kk + 1) & 3;      \
      unsigned k0w, k1w, k2w, k3w, q0w, q1w, q2w, q3w;                       \
      plswap(Kp[nt][g0][0], Kp[nt][g1][0], k0w, k2w);                        \
      plswap(Kp[nt][g0][1], Kp[nt][g1][1], k1w, k3w);                        \
      plswap(Qp[nt][g0][0], Qp[nt][g1][0], q0w, q2w);                        \
      plswap(Qp[nt][g0][1], Qp[nt][g1][1], q1w, q3w);                        \
      uint4v kw = { k0w, k1w, k2w, k3w };                                    \
      uint4v qw = { q0w, q1w, q2w, q3w };                                    \
      wei = __builtin_amdgcn_mfma_f32_32x32x16_bf16(                         \
          __builtin_bit_cast(bf16x8, kw), __builtin_bit_cast(bf16x8, qw), wei, 0, 0, 0); \
    }                                                                        \
    float pv[16];                                                            \
    float m = -3.0e38f;                                                      \
    _Pragma("unroll")                                                        \
    for (int r = 0; r < 16; ++r) {                                           \
      int s = (r & 3) + 8 * (r >> 2) + 4 * hi;                               \
      float v = (s <= lo) ? wei[r] * 0.125f : -__builtin_inff();             \
      pv[r] = v;                                                             \
      m = fmaxf(m, v);                                                       \
    }                                                                        \
    m = fmaxf(m, __shfl_xor(m, 32));                                         \
    float sum = 0.0f;                                                        \
    _Pragma("unroll")                                                        \
    for (int r = 0; r < 16; ++r) {                                           \
      float e = __expf(pv[r] - m);                                           \
      pv[r] = e;                                                             \
      sum += e;                                                              \
    }                                                                        \
    sum += __shfl_xor(sum, 32);                                              \
    const float inv = 1.0f / sum;                                            \
    unsigned Pp[4][2];                                                       \
    _Pragma("unroll")                                                        \
    for (int g = 0; g < 4; ++g) {                                            \
      Pp[g][0] = pk2(pv[g * 4 + 0] * inv, pv[g * 4 + 1] * inv);              \
      Pp[g][1] = pk2(pv[g * 4 + 2] * inv, pv[g * 4 + 3] * inv);              \
    }                                                                        \
    f32x16 o[2];                                                             \
    _Pragma("unroll")                                                        \
    for (int r = 0; r < 16; ++r) { o[0][r] = bv0; o[1][r] = bv1; }           \
    _Pragma("unroll")                                                        \
    for (int kk = 0; kk < 2; ++kk) {                                         \
      const int g0 = 2 * kk, g1 = 2 * kk + 1;                                \
      unsigned p0w, p1w, p2w, p3w;                                           \
      plswap(Pp[g0][0], Pp[g1][0], p0w, p2w);                                \
      plswap(Pp[g0][1], Pp[g1][1], p1w, p3w);                                \
      uint4v pw = { p0w, p1w, p2w, p3w };                                    \
      bf16x8 pa = __builtin_bit_cast(bf16x8, pw);                            \
      _Pragma("unroll")                                                      \
      for (int nt = 0; nt < 2; ++nt) {                                       \
        unsigned v0w, v1w, v2w, v3w;                                         \
        plswap(Vp[nt][g0][0], Vp[nt][g1][0], v0w, v2w);                      \
        plswap(Vp[nt][g0][1], Vp[nt][g1][1], v1w, v3w);                      \
        uint4v vw = { v0w, v1w, v2w, v3w };                                  \
        o[nt] = __builtin_amdgcn_mfma_f32_32x32x16_bf16(                     \
            pa, __builtin_bit_cast(bf16x8, vw), o[nt], 0, 0, 0);             \
      }                                                                      \
    }                                                                        \
    float* ob = ob0 + (jj) * (TT * HEAD);                                    \
    _Pragma("unroll")                                                        \
    for (int nt = 0; nt < 2; ++nt) {                                         \
      int h = nt * 32 + lo;                                                  \
      _Pragma("unroll")                                                      \
      for (int r = 0; r < 16; ++r) {                                         \
        int row = (r & 3) + 8 * (r >> 2) + 4 * hi;                           \
        __builtin_nontemporal_store(o[nt][r], &ob[row * HEAD + h]);          \
      }                                                                      \
    }                                                                        \
  } while (0)

#pragma unroll 1
  for (int j = 0; j < NI; j += 2) {
    BODY(F0, j);
    BODY(F1, j + 1);
  }
#undef BODY
#undef ISSUE
}

extern "C" void kernel_launch(void* const* d_in, const int* in_sizes, int n_in,
                              void* d_out, int out_size, void* d_ws, size_t ws_size,
                              hipStream_t stream) {
  const float* X  = (const float*)d_in[0];
  const float* Wq = (const float*)d_in[1];
  const float* bq = (const float*)d_in[2];
  const float* Wk = (const float*)d_in[3];
  const float* bv = (const float*)d_in[6];
  const float* Wv = (const float*)d_in[5];
  float* out = (float*)d_out;
  unsigned short* Wt = (unsigned short*)d_ws;  // 192*256 bf16 = 96 KB scratch

  const int B = in_sizes[0] / (TT * EMB);  // 8192

  prep_weights<<<192, 256, 0, stream>>>(Wq, Wk, Wv, Wt);
  attn_kernel<<<B / (4 * NI), 256, 0, stream>>>(X, Wt, bq, bv, out);
}

// Round 11
// 65.296 us; speedup vs baseline: 2.0779x; 2.0779x over previous
//
#include <hip/hip_runtime.h>

#define TT 32
#define EMB 256
#define HEAD 64
#define NI 8   // items per wave; grid = 8192/(4*NI) = 256 = one block per CU

typedef __attribute__((ext_vector_type(8)))  short    bf16x8;
typedef __attribute__((ext_vector_type(16))) float    f32x16;
typedef __attribute__((ext_vector_type(4)))  float    f32x4;
typedef __attribute__((ext_vector_type(4)))  unsigned uint4v;

__device__ __forceinline__ unsigned bfr(float f) {   // bf16 bits (RNE), low 16
  unsigned u = __builtin_bit_cast(unsigned, f);
  u += 0x7fffu + ((u >> 16) & 1u);
  return u >> 16;
}
__device__ __forceinline__ unsigned pk2(float a, float b) {  // lo=a, hi=b
  unsigned r;
  asm("v_cvt_pk_bf16_f32 %0, %1, %2" : "=v"(r) : "v"(a), "v"(b));
  return r;
}
__device__ __forceinline__ void plswap(unsigned a, unsigned b,
                                       unsigned& x, unsigned& y) {
  auto r = __builtin_amdgcn_permlane32_swap(a, b, false, false);
  x = r[0]; y = r[1];
}

// Wt[n][k] = W_{n/64}[k][n%64] bf16, stored SWIZZLED: u16 idx = n*256 + (k ^ ((n&7)<<3))
__global__ void prep_weights(const float* __restrict__ Wq,
                             const float* __restrict__ Wk,
                             const float* __restrict__ Wv,
                             unsigned short* __restrict__ Wt) {
  int idx = blockIdx.x * 256 + threadIdx.x;   // 192*256 total
  int n = idx >> 8, k = idx & 255;
  const float* W = (n < 64) ? Wq : (n < 128) ? Wk : Wv;
  Wt[n * 256 + (k ^ ((n & 7) << 3))] = (unsigned short)bfr(W[k * 64 + (n & 63)]);
}

// R5 structure (verified passing @79us), minus the inline-asm s_waitcnt:
// the compiler's waitcnt insertion owns all load->use waits (it tracks the
// loop-carried F dependency exactly). block = 4 waves; Wt staged once in LDS
// (96 KB); each wave computes NI items, X pipelined one item ahead in VGPRs.
__global__ __launch_bounds__(256, 1)
void attn_kernel(const float* __restrict__ X,
                 const unsigned short* __restrict__ Wt,
                 const float* __restrict__ bq,
                 const float* __restrict__ bv,
                 float* __restrict__ out) {
  __shared__ unsigned short sW[192 * 256];   // 96 KB, swizzled layout

  const int tid  = threadIdx.x;
  const int wid  = tid >> 6;
  const int lane = tid & 63;
  const int lo   = lane & 31;   // MFMA tile row/col
  const int hi   = lane >> 5;   // k-half selector

  // ---- stage Wt -> LDS: linear 24 KB per wave (layout pre-swizzled) ----
  {
    const unsigned short* src = Wt + wid * 12288 + lane * 8;
#pragma unroll
    for (int i = 0; i < 24; ++i) {
      __builtin_amdgcn_global_load_lds(
          (const __attribute__((address_space(1))) void*)(src + i * 512),
          (__attribute__((address_space(3))) void*)(&sW[wid * 12288 + i * 512]),
          16, 0, 0);
    }
  }

  const long itemBase = (long)blockIdx.x * (4 * NI) + wid * NI;
  const float* Xb0 = X + itemBase * (TT * EMB);
  float* ob0 = out + itemBase * (TT * HEAD);

  // ---- loop-invariant bias regs ----
  // bq as Q-acc init (C layout: col t=lo, row h=(r&3)+8*(r>>2)+4*hi+32nt)
  f32x16 bQ2[2];
#pragma unroll
  for (int nt = 0; nt < 2; ++nt)
#pragma unroll
    for (int g = 0; g < 4; ++g) {
      f32x4 t = *(const f32x4*)(bq + nt * 32 + g * 8 + hi * 4);
#pragma unroll
      for (int q = 0; q < 4; ++q) bQ2[nt][g * 4 + q] = t[q];
    }
  // bv folds into PV accumulator init (softmax rows sum to 1); bk cancels.
  const float bv0 = bv[lo], bv1 = bv[32 + lo];

  const float* XpBase = Xb0 + lo * EMB + hi * 8;

#define ISSUE(jj)                                                            \
  do {                                                                       \
    const float* Xp_ = XpBase + (jj) * (TT * EMB);                           \
    _Pragma("unroll")                                                        \
    for (int i_ = 0; i_ < 32; ++i_)                                          \
      F[i_] = *(const f32x4*)(Xp_ + (i_ >> 1) * 16 + (i_ & 1) * 4);          \
  } while (0)

  f32x4 F[32];
  ISSUE(0);           // prologue: item 0 in flight

  __syncthreads();    // drains vmcnt+lgkmcnt: sW and F[item0] both ready

#pragma unroll 1
  for (int j = 0; j < NI; ++j) {
    // ---- cvt F -> bf16 fragments for item j ----
    // (compiler inserts the vmcnt wait for F's loads, issued a full body ago)
    uint4v Bf[16];
#pragma unroll
    for (int kk = 0; kk < 16; ++kk) {
      Bf[kk][0] = pk2(F[kk * 2][0],     F[kk * 2][1]);
      Bf[kk][1] = pk2(F[kk * 2][2],     F[kk * 2][3]);
      Bf[kk][2] = pk2(F[kk * 2 + 1][0], F[kk * 2 + 1][1]);
      Bf[kk][3] = pk2(F[kk * 2 + 1][2], F[kk * 2 + 1][3]);
    }
    __builtin_amdgcn_sched_barrier(0);

    // ---- issue item j+1 X loads (overlap with this item's compute) ----
    if (j + 1 < NI) { ISSUE(j + 1); }
    __builtin_amdgcn_sched_barrier(0);

    // ---- projection: QT,KT = W^T·X^T ; V = X·Wv  (weights from LDS) ----
    f32x16 aQ[2], aK[2], aV[2];
    aQ[0] = bQ2[0]; aQ[1] = bQ2[1];
#pragma unroll
    for (int nt = 0; nt < 2; ++nt)
#pragma unroll
      for (int r = 0; r < 16; ++r) { aK[nt][r] = 0.0f; aV[nt][r] = 0.0f; }

#pragma unroll
    for (int kk = 0; kk < 16; ++kk) {
      bf16x8 a = __builtin_bit_cast(bf16x8, Bf[kk]);
      const int csw = (kk * 16 + hi * 8) ^ ((lo & 7) << 3);  // swizzled u16 col
#pragma unroll
      for (int nt = 0; nt < 2; ++nt) {
        bf16x8 wq = *(const bf16x8*)&sW[(nt * 32 + lo) * 256 + csw];
        aQ[nt] = __builtin_amdgcn_mfma_f32_32x32x16_bf16(wq, a, aQ[nt], 0, 0, 0);
        bf16x8 wk = *(const bf16x8*)&sW[(64 + nt * 32 + lo) * 256 + csw];
        aK[nt] = __builtin_amdgcn_mfma_f32_32x32x16_bf16(wk, a, aK[nt], 0, 0, 0);
        bf16x8 wv = *(const bf16x8*)&sW[(128 + nt * 32 + lo) * 256 + csw];
        aV[nt] = __builtin_amdgcn_mfma_f32_32x32x16_bf16(a, wv, aV[nt], 0, 0, 0);
      }
    }

    // ---- pack as bf16 pairs along q: [nt][g][pair] ----
    unsigned Qp[2][4][2], Kp[2][4][2], Vp[2][4][2];
#pragma unroll
    for (int nt = 0; nt < 2; ++nt)
#pragma unroll
      for (int g = 0; g < 4; ++g) {
        Qp[nt][g][0] = pk2(aQ[nt][g * 4 + 0], aQ[nt][g * 4 + 1]);
        Qp[nt][g][1] = pk2(aQ[nt][g * 4 + 2], aQ[nt][g * 4 + 3]);
        Kp[nt][g][0] = pk2(aK[nt][g * 4 + 0], aK[nt][g * 4 + 1]);
        Kp[nt][g][1] = pk2(aK[nt][g * 4 + 2], aK[nt][g * 4 + 3]);
        Vp[nt][g][0] = pk2(aV[nt][g * 4 + 0], aV[nt][g * 4 + 1]);
        Vp[nt][g][1] = pk2(aV[nt][g * 4 + 2], aV[nt][g * 4 + 3]);
      }

    // ---- QK^T (swapped): weiT = K · Q^T ----
    f32x16 wei;
#pragma unroll
    for (int r = 0; r < 16; ++r) wei[r] = 0.0f;
#pragma unroll
    for (int kk = 0; kk < 4; ++kk) {
      const int nt = kk >> 1, g0 = (2 * kk) & 3, g1 = (2 * kk + 1) & 3;
      unsigned k0w, k1w, k2w, k3w, q0w, q1w, q2w, q3w;
      plswap(Kp[nt][g0][0], Kp[nt][g1][0], k0w, k2w);
      plswap(Kp[nt][g0][1], Kp[nt][g1][1], k1w, k3w);
      plswap(Qp[nt][g0][0], Qp[nt][g1][0], q0w, q2w);
      plswap(Qp[nt][g0][1], Qp[nt][g1][1], q1w, q3w);
      uint4v kw = { k0w, k1w, k2w, k3w };
      uint4v qw = { q0w, q1w, q2w, q3w };
      wei = __builtin_amdgcn_mfma_f32_32x32x16_bf16(
          __builtin_bit_cast(bf16x8, kw), __builtin_bit_cast(bf16x8, qw), wei, 0, 0, 0);
    }

    // ---- softmax over s for query t=lo (lane pairs l, l^32) ----
    float pv[16];
    float m = -3.0e38f;
#pragma unroll
    for (int r = 0; r < 16; ++r) {
      int s = (r & 3) + 8 * (r >> 2) + 4 * hi;
      float v = (s <= lo) ? wei[r] * 0.125f : -__builtin_inff();
      pv[r] = v;
      m = fmaxf(m, v);
    }
    m = fmaxf(m, __shfl_xor(m, 32));
    float sum = 0.0f;
#pragma unroll
    for (int r = 0; r < 16; ++r) {
      float e = __expf(pv[r] - m);
      pv[r] = e;
      sum += e;
    }
    sum += __shfl_xor(sum, 32);
    const float inv = 1.0f / sum;

    unsigned Pp[4][2];
#pragma unroll
    for (int g = 0; g < 4; ++g) {
      Pp[g][0] = pk2(pv[g * 4 + 0] * inv, pv[g * 4 + 1] * inv);
      Pp[g][1] = pk2(pv[g * 4 + 2] * inv, pv[g * 4 + 3] * inv);
    }

    // ---- out = P · V  (+ bv via acc init; softmax row-sum = 1) ----
    f32x16 o[2];
#pragma unroll
    for (int r = 0; r < 16; ++r) { o[0][r] = bv0; o[1][r] = bv1; }

#pragma unroll
    for (int kk = 0; kk < 2; ++kk) {
      const int g0 = 2 * kk, g1 = 2 * kk + 1;
      unsigned p0w, p1w, p2w, p3w;
      plswap(Pp[g0][0], Pp[g1][0], p0w, p2w);
      plswap(Pp[g0][1], Pp[g1][1], p1w, p3w);
      uint4v pw = { p0w, p1w, p2w, p3w };
      bf16x8 pa = __builtin_bit_cast(bf16x8, pw);
#pragma unroll
      for (int nt = 0; nt < 2; ++nt) {
        unsigned v0w, v1w, v2w, v3w;
        plswap(Vp[nt][g0][0], Vp[nt][g1][0], v0w, v2w);
        plswap(Vp[nt][g0][1], Vp[nt][g1][1], v1w, v3w);
        uint4v vw = { v0w, v1w, v2w, v3w };
        o[nt] = __builtin_amdgcn_mfma_f32_32x32x16_bf16(
            pa, __builtin_bit_cast(bf16x8, vw), o[nt], 0, 0, 0);
      }
    }

    // ---- stores (nontemporal, R6-proven; 2x128B segments per instr) ----
    float* ob = ob0 + j * (TT * HEAD);
#pragma unroll
    for (int nt = 0; nt < 2; ++nt) {
      int h = nt * 32 + lo;
#pragma unroll
      for (int r = 0; r < 16; ++r) {
        int row = (r & 3) + 8 * (r >> 2) + 4 * hi;
        __builtin_nontemporal_store(o[nt][r], &ob[row * HEAD + h]);
      }
    }
  }
#undef ISSUE
}

extern "C" void kernel_launch(void* const* d_in, const int* in_sizes, int n_in,
                              void* d_out, int out_size, void* d_ws, size_t ws_size,
                              hipStream_t stream) {
  const float* X  = (const float*)d_in[0];
  const float* Wq = (const float*)d_in[1];
  const float* bq = (const float*)d_in[2];
  const float* Wk = (const float*)d_in[3];
  const float* bv = (const float*)d_in[6];
  const float* Wv = (const float*)d_in[5];
  float* out = (float*)d_out;
  unsigned short* Wt = (unsigned short*)d_ws;  // 192*256 bf16 = 96 KB scratch

  const int B = in_sizes[0] / (TT * EMB);  // 8192

  prep_weights<<<192, 256, 0, stream>>>(Wq, Wk, Wv, Wt);
  attn_kernel<<<B / (4 * NI), 256, 0, stream>>>(X, Wt, bq, bv, out);
}

// Round 12
// 62.703 us; speedup vs baseline: 2.1638x; 1.0414x over previous
//
#include <hip/hip_runtime.h>

#define TT 32
#define EMB 256
#define HEAD 64
#define NI 8   // items per wave; grid = 8192/(4*NI) = 256 = one block per CU

typedef __attribute__((ext_vector_type(8)))  short    bf16x8;
typedef __attribute__((ext_vector_type(16))) float    f32x16;
typedef __attribute__((ext_vector_type(4)))  float    f32x4;
typedef __attribute__((ext_vector_type(4)))  unsigned uint4v;

__device__ __forceinline__ unsigned bfr(float f) {   // bf16 bits (RNE), low 16
  unsigned u = __builtin_bit_cast(unsigned, f);
  u += 0x7fffu + ((u >> 16) & 1u);
  return u >> 16;
}
__device__ __forceinline__ unsigned pk2(float a, float b) {  // lo=a, hi=b
  unsigned r;
  asm("v_cvt_pk_bf16_f32 %0, %1, %2" : "=v"(r) : "v"(a), "v"(b));
  return r;
}
__device__ __forceinline__ void plswap(unsigned a, unsigned b,
                                       unsigned& x, unsigned& y) {
  auto r = __builtin_amdgcn_permlane32_swap(a, b, false, false);
  x = r[0]; y = r[1];
}

// Wt[n][k] = W_{n/64}[k][n%64] bf16, stored SWIZZLED: u16 idx = n*256 + (k ^ ((n&7)<<3))
__global__ void prep_weights(const float* __restrict__ Wq,
                             const float* __restrict__ Wk,
                             const float* __restrict__ Wv,
                             unsigned short* __restrict__ Wt) {
  int idx = blockIdx.x * 256 + threadIdx.x;   // 192*256 total
  int n = idx >> 8, k = idx & 255;
  const float* W = (n < 64) ? Wq : (n < 128) ? Wk : Wv;
  Wt[n * 256 + (k ^ ((n & 7) << 3))] = (unsigned short)bfr(W[k * 64 + (n & 63)]);
}

// R11 base (verified 65.3us), one delta: next-item X loads issued in 4 chunks
// of 8 spread through the MFMA loop (kk=0,4,8,12) instead of one burst —
// smooths each wave's VMEM request stream to ~100% duty cycle. No inline-asm
// waits anywhere: the compiler's waitcnt pass owns all load->use ordering.
__global__ __launch_bounds__(256, 1)
void attn_kernel(const float* __restrict__ X,
                 const unsigned short* __restrict__ Wt,
                 const float* __restrict__ bq,
                 const float* __restrict__ bv,
                 float* __restrict__ out) {
  __shared__ unsigned short sW[192 * 256];   // 96 KB, swizzled layout

  const int tid  = threadIdx.x;
  const int wid  = tid >> 6;
  const int lane = tid & 63;
  const int lo   = lane & 31;   // MFMA tile row/col
  const int hi   = lane >> 5;   // k-half selector

  // ---- stage Wt -> LDS: linear 24 KB per wave (layout pre-swizzled) ----
  {
    const unsigned short* src = Wt + wid * 12288 + lane * 8;
#pragma unroll
    for (int i = 0; i < 24; ++i) {
      __builtin_amdgcn_global_load_lds(
          (const __attribute__((address_space(1))) void*)(src + i * 512),
          (__attribute__((address_space(3))) void*)(&sW[wid * 12288 + i * 512]),
          16, 0, 0);
    }
  }

  const long itemBase = (long)blockIdx.x * (4 * NI) + wid * NI;
  const float* Xb0 = X + itemBase * (TT * EMB);
  float* ob0 = out + itemBase * (TT * HEAD);

  // ---- loop-invariant bias regs ----
  // bq as Q-acc init (C layout: col t=lo, row h=(r&3)+8*(r>>2)+4*hi+32nt)
  f32x16 bQ2[2];
#pragma unroll
  for (int nt = 0; nt < 2; ++nt)
#pragma unroll
    for (int g = 0; g < 4; ++g) {
      f32x4 t = *(const f32x4*)(bq + nt * 32 + g * 8 + hi * 4);
#pragma unroll
      for (int q = 0; q < 4; ++q) bQ2[nt][g * 4 + q] = t[q];
    }
  // bv folds into PV accumulator init (softmax rows sum to 1); bk cancels.
  const float bv0 = bv[lo], bv1 = bv[32 + lo];

  const float* XpBase = Xb0 + lo * EMB + hi * 8;

  // chunk c of item jj: 8 x dwordx4 into F[c*8 .. c*8+7]
#define ISSUE_CHUNK(jj, c)                                                   \
  do {                                                                       \
    const float* Xp_ = XpBase + (jj) * (TT * EMB);                           \
    _Pragma("unroll")                                                        \
    for (int i_ = (c) * 8; i_ < (c) * 8 + 8; ++i_)                           \
      F[i_] = *(const f32x4*)(Xp_ + (i_ >> 1) * 16 + (i_ & 1) * 4);          \
  } while (0)

  f32x4 F[32];
  ISSUE_CHUNK(0, 0); ISSUE_CHUNK(0, 1); ISSUE_CHUNK(0, 2); ISSUE_CHUNK(0, 3);

  __syncthreads();    // drains vmcnt+lgkmcnt: sW and F[item0] both ready

#pragma unroll 1
  for (int j = 0; j < NI; ++j) {
    // ---- cvt F -> bf16 fragments for item j ----
    // (compiler inserts incremental vmcnt waits for F's loads as needed)
    uint4v Bf[16];
#pragma unroll
    for (int kk = 0; kk < 16; ++kk) {
      Bf[kk][0] = pk2(F[kk * 2][0],     F[kk * 2][1]);
      Bf[kk][1] = pk2(F[kk * 2][2],     F[kk * 2][3]);
      Bf[kk][2] = pk2(F[kk * 2 + 1][0], F[kk * 2 + 1][1]);
      Bf[kk][3] = pk2(F[kk * 2 + 1][2], F[kk * 2 + 1][3]);
    }
    __builtin_amdgcn_sched_barrier(0);

    // ---- projection: QT,KT = W^T·X^T ; V = X·Wv  (weights from LDS);
    //      next-item loads issued in 4 chunks at kk = 0,4,8,12 ----
    f32x16 aQ[2], aK[2], aV[2];
    aQ[0] = bQ2[0]; aQ[1] = bQ2[1];
#pragma unroll
    for (int nt = 0; nt < 2; ++nt)
#pragma unroll
      for (int r = 0; r < 16; ++r) { aK[nt][r] = 0.0f; aV[nt][r] = 0.0f; }

#pragma unroll
    for (int kk = 0; kk < 16; ++kk) {
      if ((kk & 3) == 0 && j + 1 < NI) { ISSUE_CHUNK(j + 1, kk >> 2); }
      bf16x8 a = __builtin_bit_cast(bf16x8, Bf[kk]);
      const int csw = (kk * 16 + hi * 8) ^ ((lo & 7) << 3);  // swizzled u16 col
#pragma unroll
      for (int nt = 0; nt < 2; ++nt) {
        bf16x8 wq = *(const bf16x8*)&sW[(nt * 32 + lo) * 256 + csw];
        aQ[nt] = __builtin_amdgcn_mfma_f32_32x32x16_bf16(wq, a, aQ[nt], 0, 0, 0);
        bf16x8 wk = *(const bf16x8*)&sW[(64 + nt * 32 + lo) * 256 + csw];
        aK[nt] = __builtin_amdgcn_mfma_f32_32x32x16_bf16(wk, a, aK[nt], 0, 0, 0);
        bf16x8 wv = *(const bf16x8*)&sW[(128 + nt * 32 + lo) * 256 + csw];
        aV[nt] = __builtin_amdgcn_mfma_f32_32x32x16_bf16(a, wv, aV[nt], 0, 0, 0);
      }
    }

    // ---- pack as bf16 pairs along q: [nt][g][pair] ----
    unsigned Qp[2][4][2], Kp[2][4][2], Vp[2][4][2];
#pragma unroll
    for (int nt = 0; nt < 2; ++nt)
#pragma unroll
      for (int g = 0; g < 4; ++g) {
        Qp[nt][g][0] = pk2(aQ[nt][g * 4 + 0], aQ[nt][g * 4 + 1]);
        Qp[nt][g][1] = pk2(aQ[nt][g * 4 + 2], aQ[nt][g * 4 + 3]);
        Kp[nt][g][0] = pk2(aK[nt][g * 4 + 0], aK[nt][g * 4 + 1]);
        Kp[nt][g][1] = pk2(aK[nt][g * 4 + 2], aK[nt][g * 4 + 3]);
        Vp[nt][g][0] = pk2(aV[nt][g * 4 + 0], aV[nt][g * 4 + 1]);
        Vp[nt][g][1] = pk2(aV[nt][g * 4 + 2], aV[nt][g * 4 + 3]);
      }

    // ---- QK^T (swapped): weiT = K · Q^T ----
    f32x16 wei;
#pragma unroll
    for (int r = 0; r < 16; ++r) wei[r] = 0.0f;
#pragma unroll
    for (int kk = 0; kk < 4; ++kk) {
      const int nt = kk >> 1, g0 = (2 * kk) & 3, g1 = (2 * kk + 1) & 3;
      unsigned k0w, k1w, k2w, k3w, q0w, q1w, q2w, q3w;
      plswap(Kp[nt][g0][0], Kp[nt][g1][0], k0w, k2w);
      plswap(Kp[nt][g0][1], Kp[nt][g1][1], k1w, k3w);
      plswap(Qp[nt][g0][0], Qp[nt][g1][0], q0w, q2w);
      plswap(Qp[nt][g0][1], Qp[nt][g1][1], q1w, q3w);
      uint4v kw = { k0w, k1w, k2w, k3w };
      uint4v qw = { q0w, q1w, q2w, q3w };
      wei = __builtin_amdgcn_mfma_f32_32x32x16_bf16(
          __builtin_bit_cast(bf16x8, kw), __builtin_bit_cast(bf16x8, qw), wei, 0, 0, 0);
    }

    // ---- softmax over s for query t=lo (lane pairs l, l^32) ----
    float pv[16];
    float m = -3.0e38f;
#pragma unroll
    for (int r = 0; r < 16; ++r) {
      int s = (r & 3) + 8 * (r >> 2) + 4 * hi;
      float v = (s <= lo) ? wei[r] * 0.125f : -__builtin_inff();
      pv[r] = v;
      m = fmaxf(m, v);
    }
    m = fmaxf(m, __shfl_xor(m, 32));
    float sum = 0.0f;
#pragma unroll
    for (int r = 0; r < 16; ++r) {
      float e = __expf(pv[r] - m);
      pv[r] = e;
      sum += e;
    }
    sum += __shfl_xor(sum, 32);
    const float inv = 1.0f / sum;

    unsigned Pp[4][2];
#pragma unroll
    for (int g = 0; g < 4; ++g) {
      Pp[g][0] = pk2(pv[g * 4 + 0] * inv, pv[g * 4 + 1] * inv);
      Pp[g][1] = pk2(pv[g * 4 + 2] * inv, pv[g * 4 + 3] * inv);
    }

    // ---- out = P · V  (+ bv via acc init; softmax row-sum = 1) ----
    f32x16 o[2];
#pragma unroll
    for (int r = 0; r < 16; ++r) { o[0][r] = bv0; o[1][r] = bv1; }

#pragma unroll
    for (int kk = 0; kk < 2; ++kk) {
      const int g0 = 2 * kk, g1 = 2 * kk + 1;
      unsigned p0w, p1w, p2w, p3w;
      plswap(Pp[g0][0], Pp[g1][0], p0w, p2w);
      plswap(Pp[g0][1], Pp[g1][1], p1w, p3w);
      uint4v pw = { p0w, p1w, p2w, p3w };
      bf16x8 pa = __builtin_bit_cast(bf16x8, pw);
#pragma unroll
      for (int nt = 0; nt < 2; ++nt) {
        unsigned v0w, v1w, v2w, v3w;
        plswap(Vp[nt][g0][0], Vp[nt][g1][0], v0w, v2w);
        plswap(Vp[nt][g0][1], Vp[nt][g1][1], v1w, v3w);
        uint4v vw = { v0w, v1w, v2w, v3w };
        o[nt] = __builtin_amdgcn_mfma_f32_32x32x16_bf16(
            pa, __builtin_bit_cast(bf16x8, vw), o[nt], 0, 0, 0);
      }
    }

    // ---- stores (nontemporal; 2x128B segments per instr) ----
    float* ob = ob0 + j * (TT * HEAD);
#pragma unroll
    for (int nt = 0; nt < 2; ++nt) {
      int h = nt * 32 + lo;
#pragma unroll
      for (int r = 0; r < 16; ++r) {
        int row = (r & 3) + 8 * (r >> 2) + 4 * hi;
        __builtin_nontemporal_store(o[nt][r], &ob[row * HEAD + h]);
      }
    }
  }
#undef ISSUE_CHUNK
}

extern "C" void kernel_launch(void* const* d_in, const int* in_sizes, int n_in,
                              void* d_out, int out_size, void* d_ws, size_t ws_size,
                              hipStream_t stream) {
  const float* X  = (const float*)d_in[0];
  const float* Wq = (const float*)d_in[1];
  const float* bq = (const float*)d_in[2];
  const float* Wk = (const float*)d_in[3];
  const float* bv = (const float*)d_in[6];
  const float* Wv = (const float*)d_in[5];
  float* out = (float*)d_out;
  unsigned short* Wt = (unsigned short*)d_ws;  // 192*256 bf16 = 96 KB scratch

  const int B = in_sizes[0] / (TT * EMB);  // 8192

  prep_weights<<<192, 256, 0, stream>>>(Wq, Wk, Wv, Wt);
  attn_kernel<<<B / (4 * NI), 256, 0, stream>>>(X, Wt, bq, bv, out);
}